// Round 8
// baseline (781.145 us; speedup 1.0000x reference)
//
#include <hip/hip_runtime.h>
#include <math.h>

#define Bv 256
#define Sv 128
#define Cv 256
#define Tv 64
#define Dv 300
#define Hv 150
#define G4v 600   // 4*H

typedef _Float16 h8v __attribute__((ext_vector_type(8)));
typedef _Float16 h4v __attribute__((ext_vector_type(4)));
typedef float    f4v __attribute__((ext_vector_type(4)));
typedef float    f2v __attribute__((ext_vector_type(2)));

// ------------------------------------------------------------------
// row L2 norm (length 300), one wave per row: out[r] = max(||x_r||, 1e-8)
// ------------------------------------------------------------------
__global__ __launch_bounds__(256)
void row_norm_k(const float* __restrict__ x, int rows, float* __restrict__ out)
{
    int gtid = blockIdx.x * 256 + threadIdx.x;
    int wave = gtid >> 6;
    int lane = threadIdx.x & 63;
    if (wave >= rows) return;
    const float* row = x + (size_t)wave * Dv;
    float s = 0.f;
    for (int k = lane; k < Dv; k += 64) { float v = row[k]; s += v * v; }
    #pragma unroll
    for (int off = 32; off > 0; off >>= 1) s += __shfl_down(s, off, 64);
    if (lane == 0) out[wave] = fmaxf(sqrtf(s), 1e-8f);
}

// ------------------------------------------------------------------
// generic fp32 [rows][300] -> fp16 [rows][320] (k>=300 zero)
// ------------------------------------------------------------------
__global__ __launch_bounds__(256)
void conv_a16_k(const float* __restrict__ A, _Float16* __restrict__ A16)
{
    int idx = blockIdx.x * 256 + threadIdx.x;
    int row = idx / 80;
    int k   = (idx - row * 80) * 4;
    float4 v = {0.f, 0.f, 0.f, 0.f};
    if (k < Dv) v = *(const float4*)&A[(size_t)row * Dv + k];
    h4v o;
    o[0] = (_Float16)v.x; o[1] = (_Float16)v.y;
    o[2] = (_Float16)v.z; o[3] = (_Float16)v.w;
    *(h4v*)&A16[(size_t)row * 320 + k] = o;
}

// ------------------------------------------------------------------
// Wx fp32 [300][600] -> W16T fp16 [dir][640][320] transposed, zero-padded
// ------------------------------------------------------------------
__global__ __launch_bounds__(320)
void conv_w16_k(const float* __restrict__ Wf, const float* __restrict__ Wb,
                _Float16* __restrict__ W16T)
{
    const int n   = blockIdx.x;      // 0..639
    const int dir = blockIdx.y;      // 0..1
    const int k   = threadIdx.x;     // 0..319
    const float* W = dir ? Wb : Wf;
    float v = (k < Dv && n < G4v) ? W[(size_t)k * G4v + n] : 0.f;
    W16T[((size_t)dir * 640 + n) * 320 + k] = (_Float16)v;
}

// ------------------------------------------------------------------
// MFMA input projection: G[dir][s][b][0:600] = src @ Wx_dir + b_dir
// ------------------------------------------------------------------
__global__ __launch_bounds__(256)
void gemm_xw_mfma_k(const _Float16* __restrict__ A16,
                    const _Float16* __restrict__ W16T,
                    const float* __restrict__ bf, const float* __restrict__ bb,
                    float* __restrict__ Gout)
{
    const int m0  = blockIdx.x * 128;
    const int n0  = blockIdx.y * 128;
    const int dir = blockIdx.z;
    const float* bias = dir ? bb : bf;
    const _Float16* Wd = W16T + (size_t)dir * 640 * 320;

    __shared__ _Float16 As[128][40];
    __shared__ _Float16 Bs[128][40];

    const int tid  = threadIdx.x;
    const int lane = tid & 63;
    const int w    = tid >> 6;
    const int wm   = w >> 1, wn = w & 1;
    const int r16  = lane & 15, q = lane >> 4;

    const int srow  = tid >> 1;
    const int sslot = (tid & 1) * 16;

    f4v acc[4][4];
    #pragma unroll
    for (int i = 0; i < 4; ++i)
        #pragma unroll
        for (int j = 0; j < 4; ++j) acc[i][j] = (f4v){0.f,0.f,0.f,0.f};

    for (int k0 = 0; k0 < 320; k0 += 32) {
        h8v av0 = *(const h8v*)&A16[(size_t)(m0 + srow) * 320 + k0 + sslot];
        h8v av1 = *(const h8v*)&A16[(size_t)(m0 + srow) * 320 + k0 + sslot + 8];
        h8v bv0 = *(const h8v*)&Wd [(size_t)(n0 + srow) * 320 + k0 + sslot];
        h8v bv1 = *(const h8v*)&Wd [(size_t)(n0 + srow) * 320 + k0 + sslot + 8];
        __syncthreads();
        *(h8v*)&As[srow][sslot]     = av0;
        *(h8v*)&As[srow][sslot + 8] = av1;
        *(h8v*)&Bs[srow][sslot]     = bv0;
        *(h8v*)&Bs[srow][sslot + 8] = bv1;
        __syncthreads();

        h8v af[4], bfr[4];
        #pragma unroll
        for (int mi = 0; mi < 4; ++mi)
            af[mi] = *(const h8v*)&As[wm*64 + mi*16 + r16][q*8];
        #pragma unroll
        for (int ni = 0; ni < 4; ++ni)
            bfr[ni] = *(const h8v*)&Bs[wn*64 + ni*16 + r16][q*8];
        #pragma unroll
        for (int mi = 0; mi < 4; ++mi)
            #pragma unroll
            for (int ni = 0; ni < 4; ++ni)
                acc[mi][ni] = __builtin_amdgcn_mfma_f32_16x16x32_f16(
                                  af[mi], bfr[ni], acc[mi][ni], 0, 0, 0);
    }

    #pragma unroll
    for (int ni = 0; ni < 4; ++ni) {
        int n = n0 + wn*64 + ni*16 + r16;
        if (n >= G4v) continue;
        float bn = bias[n];
        #pragma unroll
        for (int mi = 0; mi < 4; ++mi) {
            #pragma unroll
            for (int r = 0; r < 4; ++r) {
                int row = m0 + wm*64 + mi*16 + q*4 + r;
                int b   = row >> 7;
                int s   = row & 127;
                Gout[(((size_t)dir * Sv + s) * Bv + b) * G4v + n] = acc[mi][ni][r] + bn;
            }
        }
    }
}

// ------------------------------------------------------------------
// fast transcendentals: v_exp/v_rcp based (~1e-6 rel err, far below the
// fp16-h quantization already in the pipeline)
// ------------------------------------------------------------------
__device__ __forceinline__ float sigm_f(float x)
{
    return __builtin_amdgcn_rcpf(1.f + __expf(-x));
}
__device__ __forceinline__ float tanh_f(float x)
{
    float e = __expf(-2.f * __builtin_fabsf(x));
    float r = (1.f - e) * __builtin_amdgcn_rcpf(1.f + e);
    return __builtin_copysignf(r, x);
}

// ------------------------------------------------------------------
// MFMA LSTM recurrence v3b. 32 blocks = 16 batch-groups x 2 dirs.
// A = Wh^T (register-resident), B = h (LDS, col=batch), C = G prefetch.
// D[row=n][col=batch]: lane (q,cp) holds gates for batch cp, units
// nb..nb+3 in registers. FIX vs v3: the G/C-operand tail load is now two
// guarded f2v pairs (lo: nb<Hv, hi: nb+2<Hv) -- the old whole-f4v clamp
// redirected g=3,nb=148 to the i-gate row (units 148/149 corrupted).
// ------------------------------------------------------------------
__global__ __launch_bounds__(640, 1)
void lstm_mfma_k(const float* __restrict__ G,      // [2][S][B][600] bias incl.
                 const float* __restrict__ Wh_f, const float* __restrict__ Wh_b,
                 float* __restrict__ out_src,      // [B][S][300]
                 float* __restrict__ out_cell)     // [B][300]
{
    const int blk = blockIdx.x;          // 0..31
    const int dir = blk & 1;
    const int b0  = (blk >> 1) * 16;
    const float* Wh = dir ? Wh_b : Wh_f;
    const float* Gd = G + (size_t)dir * Sv * Bv * G4v;

    const int tid  = threadIdx.x;
    const int w    = tid >> 6;           // wave 0..9
    const int lane = tid & 63;
    const int q    = lane >> 4;          // 0..3
    const int cp   = lane & 15;          // 0..15 (batch col)
    const int nb   = w * 16 + 4 * q;     // first of this lane's 4 hidden units
    const int ncol = w * 16 + cp;        // A-frag row (hidden unit) this lane loads
    const int batch = b0 + cp;

    __shared__ _Float16 h_sh[2][16][168];

    // ---- one-time: A-frags = Wh^T (rows = n, k = hidden) in registers ----
    h8v Af[4][5];
    #pragma unroll
    for (int g = 0; g < 4; ++g) {
        #pragma unroll
        for (int ks = 0; ks < 5; ++ks) {
            h8v v;
            #pragma unroll
            for (int j = 0; j < 8; ++j) {
                int k = 32*ks + 8*q + j;
                float x = (k < Hv && ncol < Hv)
                        ? Wh[(size_t)k * G4v + g*Hv + ncol] : 0.f;
                v[j] = (_Float16)x;
            }
            Af[g][ks] = v;
        }
    }

    for (int i = tid; i < 2*16*168; i += 640)
        ((_Float16*)h_sh)[i] = (_Float16)0.f;

    float cst[4] = {0.f, 0.f, 0.f, 0.f};

    // prefetch G (C-operand) for step 0: guarded f2v pairs, always in-row
    f4v gc[4];
    {
        int ss0 = dir ? (Sv - 1) : 0;
        const float* gp = Gd + ((size_t)ss0 * Bv + batch) * G4v + nb;
        #pragma unroll
        for (int g = 0; g < 4; ++g) {
            const float* p = gp + g*Hv;
            f2v lo = (nb     < Hv) ? *(const f2v*)p       : (f2v){0.f,0.f};
            f2v hi = (nb + 2 < Hv) ? *(const f2v*)(p + 2) : (f2v){0.f,0.f};
            gc[g] = (f4v){lo[0], lo[1], hi[0], hi[1]};
        }
    }
    __syncthreads();

    int cur = 0;
    for (int s = 0; s < Sv; ++s) {
        const int ss = dir ? (Sv - 1 - s) : s;

        // ---- prefetch next step's G (raw barrier below won't drain it) ----
        f4v gn[4];
        #pragma unroll
        for (int g = 0; g < 4; ++g) gn[g] = (f4v){0.f,0.f,0.f,0.f};
        if (s + 1 < Sv) {
            int ssn = dir ? (ss - 1) : (ss + 1);
            const float* gp = Gd + ((size_t)ssn * Bv + batch) * G4v + nb;
            #pragma unroll
            for (int g = 0; g < 4; ++g) {
                const float* p = gp + g*Hv;
                f2v lo = (nb     < Hv) ? *(const f2v*)p       : (f2v){0.f,0.f};
                f2v hi = (nb + 2 < Hv) ? *(const f2v*)(p + 2) : (f2v){0.f,0.f};
                gn[g] = (f4v){lo[0], lo[1], hi[0], hi[1]};
            }
        }

        // ---- MFMA: acc[g] = Wh^T(g) @ h + G(g)  (C preloaded with G) ----
        f4v a0 = gc[0], a1 = gc[1], a2 = gc[2], a3 = gc[3];
        #pragma unroll
        for (int ks = 0; ks < 5; ++ks) {
            h8v bf = *(const h8v*)&h_sh[cur][cp][32*ks + 8*q];
            a0 = __builtin_amdgcn_mfma_f32_16x16x32_f16(Af[0][ks], bf, a0, 0, 0, 0);
            a1 = __builtin_amdgcn_mfma_f32_16x16x32_f16(Af[1][ks], bf, a1, 0, 0, 0);
            a2 = __builtin_amdgcn_mfma_f32_16x16x32_f16(Af[2][ks], bf, a2, 0, 0, 0);
            a3 = __builtin_amdgcn_mfma_f32_16x16x32_f16(Af[3][ks], bf, a3, 0, 0, 0);
        }

        // ---- gate math fully in-register (4 hidden units per lane) ----
        float hv[4];
        #pragma unroll
        for (int r = 0; r < 4; ++r) {
            float I  = sigm_f(a0[r]);
            float F  = sigm_f(a1[r]);
            float Gt = tanh_f(a2[r]);
            float O  = sigm_f(a3[r]);
            cst[r] = F * cst[r] + I * Gt;
            float h = O * tanh_f(cst[r]);
            hv[r] = (nb + r < Hv) ? h : 0.f;
        }

        // h -> next buffer: one b64 write (4 contiguous halves)
        h4v hp;
        hp[0] = (_Float16)hv[0]; hp[1] = (_Float16)hv[1];
        hp[2] = (_Float16)hv[2]; hp[3] = (_Float16)hv[3];
        *(h4v*)&h_sh[cur ^ 1][cp][nb] = hp;

        // out_src: two guarded 8B stores
        {
            float* op = out_src + ((size_t)batch * Sv + ss) * (2*Hv) + dir*Hv + nb;
            if (nb < Hv)     *(f2v*)op       = (f2v){hv[0], hv[1]};
            if (nb + 2 < Hv) *(f2v*)(op + 2) = (f2v){hv[2], hv[3]};
        }

        gc[0] = gn[0]; gc[1] = gn[1]; gc[2] = gn[2]; gc[3] = gn[3];
        cur ^= 1;

        // lgkmcnt-only barrier (LDS visibility; VMEM stays in flight)
        asm volatile("s_waitcnt lgkmcnt(0)" ::: "memory");
        __builtin_amdgcn_s_barrier();
        __builtin_amdgcn_sched_barrier(0);
    }

    {
        float* op = out_cell + (size_t)batch * (2*Hv) + dir*Hv + nb;
        if (nb < Hv)     *(f2v*)op       = (f2v){cst[0], cst[1]};
        if (nb + 2 < Hv) *(f2v*)(op + 2) = (f2v){cst[2], cst[3]};
    }
}

// ------------------------------------------------------------------
// transpose src_encoding: out_src fp32 [B][S][300] -> hi/lo fp16 [B][320][128]
// ------------------------------------------------------------------
__global__ __launch_bounds__(256)
void trans_enc_k(const float* __restrict__ enc,
                 _Float16* __restrict__ hi, _Float16* __restrict__ lo)
{
    const int b  = blockIdx.z;
    const int s0 = blockIdx.x * 64;
    const int n0 = blockIdx.y * 64;
    __shared__ float t[64][65];
    const int tid = threadIdx.x;
    const int j  = tid & 63;
    const int i0 = (tid >> 6) * 16;
    #pragma unroll
    for (int ii = 0; ii < 16; ++ii) {
        int i = i0 + ii;
        int n = n0 + j;
        t[i][j] = (n < Dv) ? enc[((size_t)b*Sv + s0 + i)*Dv + n] : 0.f;
    }
    __syncthreads();
    #pragma unroll
    for (int ii = 0; ii < 16; ++ii) {
        int nr = i0 + ii;
        float v = t[j][nr];
        _Float16 hh = (_Float16)v;
        float l = v - (float)hh;
        size_t o = ((size_t)b*320 + n0 + nr)*128 + s0 + j;
        hi[o] = hh;
        lo[o] = (_Float16)l;
    }
}

// ------------------------------------------------------------------
// MFMA cosine-sim: sim16[b][m][s] = (cmp16[b,m,:].src16[b,s,:])/(cn*sn)
// ------------------------------------------------------------------
__global__ __launch_bounds__(256)
void gemm_sim_mfma_k(const _Float16* __restrict__ cmp16,  // [Bz][M][320]
                     const _Float16* __restrict__ src16,  // [B*128][320]
                     const float* __restrict__ cn, const float* __restrict__ sn,
                     int M, _Float16* __restrict__ sim16) // [Bz][M][128]
{
    const int m0 = blockIdx.x * 128;
    const int b  = blockIdx.z;
    const _Float16* A  = cmp16 + (size_t)b * M * 320;
    const _Float16* Bm = src16 + (size_t)b * 128 * 320;

    __shared__ _Float16 As[128][40];
    __shared__ _Float16 Bs[128][40];

    const int tid  = threadIdx.x;
    const int lane = tid & 63;
    const int w    = tid >> 6;
    const int wm   = w >> 1, wn = w & 1;
    const int r16  = lane & 15, q = lane >> 4;

    const int srow  = tid >> 1;
    const int sslot = (tid & 1) * 16;
    const int arow  = (m0 + srow < M) ? (m0 + srow) : 0;

    f4v acc[4][4];
    #pragma unroll
    for (int i = 0; i < 4; ++i)
        #pragma unroll
        for (int j = 0; j < 4; ++j) acc[i][j] = (f4v){0.f,0.f,0.f,0.f};

    for (int k0 = 0; k0 < 320; k0 += 32) {
        h8v av0 = *(const h8v*)&A [(size_t)arow * 320 + k0 + sslot];
        h8v av1 = *(const h8v*)&A [(size_t)arow * 320 + k0 + sslot + 8];
        h8v bv0 = *(const h8v*)&Bm[(size_t)srow * 320 + k0 + sslot];
        h8v bv1 = *(const h8v*)&Bm[(size_t)srow * 320 + k0 + sslot + 8];
        __syncthreads();
        *(h8v*)&As[srow][sslot]     = av0;
        *(h8v*)&As[srow][sslot + 8] = av1;
        *(h8v*)&Bs[srow][sslot]     = bv0;
        *(h8v*)&Bs[srow][sslot + 8] = bv1;
        __syncthreads();

        h8v af[4], bfr[4];
        #pragma unroll
        for (int mi = 0; mi < 4; ++mi)
            af[mi] = *(const h8v*)&As[wm*64 + mi*16 + r16][q*8];
        #pragma unroll
        for (int ni = 0; ni < 4; ++ni)
            bfr[ni] = *(const h8v*)&Bs[wn*64 + ni*16 + r16][q*8];
        #pragma unroll
        for (int mi = 0; mi < 4; ++mi)
            #pragma unroll
            for (int ni = 0; ni < 4; ++ni)
                acc[mi][ni] = __builtin_amdgcn_mfma_f32_16x16x32_f16(
                                  af[mi], bfr[ni], acc[mi][ni], 0, 0, 0);
    }

    #pragma unroll
    for (int ni = 0; ni < 4; ++ni) {
        int s = wn*64 + ni*16 + r16;
        float snv = sn[(size_t)b * 128 + s];
        #pragma unroll
        for (int mi = 0; mi < 4; ++mi) {
            #pragma unroll
            for (int r = 0; r < 4; ++r) {
                int m = m0 + wm*64 + mi*16 + q*4 + r;
                if (m < M) {
                    float v = acc[mi][ni][r] / (cn[(size_t)b * M + m] * snv);
                    sim16[((size_t)b * M + m) * 128 + s] = (_Float16)v;
                }
            }
        }
    }
}

// ------------------------------------------------------------------
// Fused context + type-encoder epilogue
// ------------------------------------------------------------------
__global__ __launch_bounds__(256, 2)
void gemm_ctx_fused_k(const _Float16* __restrict__ sim16,  // [Bz][M][128]
                      const _Float16* __restrict__ encHi,
                      const _Float16* __restrict__ encLo,  // [B][320][128]
                      const float* __restrict__ emb,       // [Bz][M][300]
                      const float* __restrict__ hot,       // [Bz][M][hd]
                      const float* __restrict__ W,         // [hd][300]
                      const float* __restrict__ bias,      // [300]
                      int M, int hd, float* __restrict__ outp)
{
    const int b  = blockIdx.z;
    const int m0 = blockIdx.x * 64;
    const int tid = threadIdx.x;
    const int lane = tid & 63;
    const int w = tid >> 6;
    const int q = lane >> 4, cp = lane & 15;

    __shared__ _Float16 As[64][136];
    __shared__ float Wsh[9*304];
    __shared__ float bsh[304];
    __shared__ float hotsh[64*9];

    {
        const int srow = tid >> 2;
        const int scol = (tid & 3) * 32;
        const _Float16* src = sim16 + ((size_t)b * M + m0 + srow) * 128 + scol;
        *(h8v*)&As[srow][scol]      = *(const h8v*)&src[0];
        *(h8v*)&As[srow][scol + 8]  = *(const h8v*)&src[8];
        *(h8v*)&As[srow][scol + 16] = *(const h8v*)&src[16];
        *(h8v*)&As[srow][scol + 24] = *(const h8v*)&src[24];
    }
    for (int i = tid; i < hd*304; i += 256) {
        int jj = i / 304, nn = i - jj*304;
        Wsh[i] = (nn < Dv) ? W[(size_t)jj * Dv + nn] : 0.f;
    }
    for (int i = tid; i < 304; i += 256) bsh[i] = (i < Dv) ? bias[i] : 0.f;
    for (int i = tid; i < 64*hd; i += 256) hotsh[i] = hot[((size_t)b * M + m0) * hd + i];
    __syncthreads();

    h8v af[4][4];
    #pragma unroll
    for (int mi = 0; mi < 4; ++mi)
        #pragma unroll
        for (int ks = 0; ks < 4; ++ks)
            af[mi][ks] = *(const h8v*)&As[mi*16 + cp][32*ks + 8*q];

    f4v acc[4][5];
    #pragma unroll
    for (int mi = 0; mi < 4; ++mi)
        #pragma unroll
        for (int nt = 0; nt < 5; ++nt) acc[mi][nt] = (f4v){0.f,0.f,0.f,0.f};

    const int nbase = w * 80;
    #pragma unroll
    for (int pass = 0; pass < 2; ++pass) {
        const _Float16* encp = pass ? encLo : encHi;
        #pragma unroll
        for (int nt = 0; nt < 5; ++nt) {
            int n = nbase + nt*16 + cp;
            const _Float16* bp = encp + ((size_t)b * 320 + n) * 128 + 8*q;
            h8v b0 = *(const h8v*)&bp[0];
            h8v b1 = *(const h8v*)&bp[32];
            h8v b2 = *(const h8v*)&bp[64];
            h8v b3 = *(const h8v*)&bp[96];
            #pragma unroll
            for (int mi = 0; mi < 4; ++mi) {
                acc[mi][nt] = __builtin_amdgcn_mfma_f32_16x16x32_f16(af[mi][0], b0, acc[mi][nt], 0, 0, 0);
                acc[mi][nt] = __builtin_amdgcn_mfma_f32_16x16x32_f16(af[mi][1], b1, acc[mi][nt], 0, 0, 0);
                acc[mi][nt] = __builtin_amdgcn_mfma_f32_16x16x32_f16(af[mi][2], b2, acc[mi][nt], 0, 0, 0);
                acc[mi][nt] = __builtin_amdgcn_mfma_f32_16x16x32_f16(af[mi][3], b3, acc[mi][nt], 0, 0, 0);
            }
        }
    }

    #pragma unroll
    for (int nt = 0; nt < 5; ++nt) {
        int n = nbase + nt*16 + cp;
        if (n >= Dv) continue;
        float bn = bsh[n];
        #pragma unroll
        for (int mi = 0; mi < 4; ++mi) {
            #pragma unroll
            for (int r = 0; r < 4; ++r) {
                int ml = mi*16 + 4*q + r;
                int m  = m0 + ml;
                float v = acc[mi][nt][r] + bn + emb[((size_t)b * M + m) * Dv + n];
                for (int jj = 0; jj < hd; ++jj)
                    v = fmaf(hotsh[ml*hd + jj], Wsh[jj*304 + n], v);
                outp[((size_t)b * M + m) * Dv + n] = v;
            }
        }
    }
}

// ------------------------------------------------------------------
extern "C" void kernel_launch(void* const* d_in, const int* in_sizes, int n_in,
                              void* d_out, int out_size, void* d_ws, size_t ws_size,
                              hipStream_t stream)
{
    (void)in_sizes; (void)n_in; (void)out_size; (void)ws_size;
    const float* src_emb = (const float*)d_in[0];
    const float* col_emb = (const float*)d_in[1];
    const float* tab_emb = (const float*)d_in[2];
    const float* col_hot = (const float*)d_in[3];
    const float* tab_hot = (const float*)d_in[4];
    const float* Wx_f = (const float*)d_in[5];
    const float* Wh_f = (const float*)d_in[6];
    const float* b_f  = (const float*)d_in[7];
    const float* Wx_b = (const float*)d_in[8];
    const float* Wh_b = (const float*)d_in[9];
    const float* b_b  = (const float*)d_in[10];
    const float* W_col = (const float*)d_in[11];
    const float* b_col = (const float*)d_in[12];
    const float* W_tab = (const float*)d_in[13];
    const float* b_tab = (const float*)d_in[14];

    float* out      = (float*)d_out;
    float* out_src  = out;                       // [256][128][300]
    float* out_col  = out + 9830400;             // [256][256][300]
    float* out_tab  = out + 29491200;            // [256][64][300]
    float* out_cell = out + 34406400;            // [256][300]

    float* ws = (float*)d_ws;
    float* Gbuf = ws;                            // 2*128*256*600 floats (157MB)
    _Float16* encHi    = (_Float16*)(ws);             // reused AFTER lstm
    _Float16* encLo    = (_Float16*)(ws + 5242880);
    _Float16* sim16_col= (_Float16*)(ws + 11000000);
    _Float16* sim16_tab= (_Float16*)(ws + 16000000);
    float* sn = ws + 39321600;
    float* cn = sn + 32768;
    float* tn = cn + 65536;

    _Float16* A16   = (_Float16*)(out + 9830400);          // [32768][320]
    _Float16* W16T  = A16 + (size_t)32768 * 320;           // [2][640][320]
    _Float16* col16 = (_Float16*)(out + 15278080);         // [65536][320]
    _Float16* tab16 = (_Float16*)(out + 29491200);         // [16384][320]

    // 0. fp16 conversions
    conv_a16_k<<<32768*80/256, 256, 0, stream>>>(src_emb, A16);
    conv_a16_k<<<65536*80/256, 256, 0, stream>>>(col_emb, col16);
    conv_a16_k<<<16384*80/256, 256, 0, stream>>>(tab_emb, tab16);
    conv_w16_k<<<dim3(640, 2), 320, 0, stream>>>(Wx_f, Wx_b, W16T);

    // 1. norms
    row_norm_k<<<32768/4, 256, 0, stream>>>(src_emb, 32768, sn);
    row_norm_k<<<65536/4, 256, 0, stream>>>(col_emb, 65536, cn);
    row_norm_k<<<16384/4, 256, 0, stream>>>(tab_emb, 16384, tn);

    // 2. input projection (MFMA)
    gemm_xw_mfma_k<<<dim3(256, 5, 2), 256, 0, stream>>>(A16, W16T, b_f, b_b, Gbuf);

    // 3. recurrence (MFMA v3b: swapped operands, G as C, fixed tail guard)
    lstm_mfma_k<<<32, 640, 0, stream>>>(Gbuf, Wh_f, Wh_b, out_src, out_cell);

    // 4. transpose + split src_encoding (Gbuf now dead)
    trans_enc_k<<<dim3(2, 5, 256), 256, 0, stream>>>(out_src, encHi, encLo);

    // 5. cosine similarity (MFMA)
    gemm_sim_mfma_k<<<dim3(2, 1, 256), 256, 0, stream>>>(col16, A16, cn, sn, 256, sim16_col);
    gemm_sim_mfma_k<<<dim3(1, 1, 256), 256, 0, stream>>>(tab16, A16, tn, sn, 64,  sim16_tab);

    // 6. fused context + type encoder
    gemm_ctx_fused_k<<<dim3(4, 1, 256), 256, 0, stream>>>(
        sim16_col, encHi, encLo, col_emb, col_hot, W_col, b_col, 256, 9, out_col);
    gemm_ctx_fused_k<<<dim3(1, 1, 256), 256, 0, stream>>>(
        sim16_tab, encHi, encLo, tab_emb, tab_hot, W_tab, b_tab, 64, 5, out_tab);
}

// Round 9
// 623.837 us; speedup vs baseline: 1.2522x; 1.2522x over previous
//
#include <hip/hip_runtime.h>
#include <math.h>

#define Bv 256
#define Sv 128
#define Cv 256
#define Tv 64
#define Dv 300
#define Hv 150
#define G4v 600   // 4*H

typedef _Float16 h8v __attribute__((ext_vector_type(8)));
typedef _Float16 h4v __attribute__((ext_vector_type(4)));
typedef float    f4v __attribute__((ext_vector_type(4)));
typedef float    f2v __attribute__((ext_vector_type(2)));

// ------------------------------------------------------------------
// row L2 norm (length 300), one wave per row: out[r] = max(||x_r||, 1e-8)
// ------------------------------------------------------------------
__global__ __launch_bounds__(256)
void row_norm_k(const float* __restrict__ x, int rows, float* __restrict__ out)
{
    int gtid = blockIdx.x * 256 + threadIdx.x;
    int wave = gtid >> 6;
    int lane = threadIdx.x & 63;
    if (wave >= rows) return;
    const float* row = x + (size_t)wave * Dv;
    float s = 0.f;
    for (int k = lane; k < Dv; k += 64) { float v = row[k]; s += v * v; }
    #pragma unroll
    for (int off = 32; off > 0; off >>= 1) s += __shfl_down(s, off, 64);
    if (lane == 0) out[wave] = fmaxf(sqrtf(s), 1e-8f);
}

// ------------------------------------------------------------------
// generic fp32 [rows][300] -> fp16 [rows][320] (k>=300 zero)
// ------------------------------------------------------------------
__global__ __launch_bounds__(256)
void conv_a16_k(const float* __restrict__ A, _Float16* __restrict__ A16)
{
    int idx = blockIdx.x * 256 + threadIdx.x;
    int row = idx / 80;
    int k   = (idx - row * 80) * 4;
    float4 v = {0.f, 0.f, 0.f, 0.f};
    if (k < Dv) v = *(const float4*)&A[(size_t)row * Dv + k];
    h4v o;
    o[0] = (_Float16)v.x; o[1] = (_Float16)v.y;
    o[2] = (_Float16)v.z; o[3] = (_Float16)v.w;
    *(h4v*)&A16[(size_t)row * 320 + k] = o;
}

// ------------------------------------------------------------------
// Wx fp32 [300][600] -> W16T fp16 [dir][640][320] transposed, zero-padded
// ------------------------------------------------------------------
__global__ __launch_bounds__(320)
void conv_w16_k(const float* __restrict__ Wf, const float* __restrict__ Wb,
                _Float16* __restrict__ W16T)
{
    const int n   = blockIdx.x;      // 0..639
    const int dir = blockIdx.y;      // 0..1
    const int k   = threadIdx.x;     // 0..319
    const float* W = dir ? Wb : Wf;
    float v = (k < Dv && n < G4v) ? W[(size_t)k * G4v + n] : 0.f;
    W16T[((size_t)dir * 640 + n) * 320 + k] = (_Float16)v;
}

// ------------------------------------------------------------------
// MFMA input projection: G16[dir][s][b][0:600] (fp16) = src @ Wx_dir + b_dir
// fp16 G: halves the stream the LSTM must pull per step and fits L3.
// ------------------------------------------------------------------
__global__ __launch_bounds__(256)
void gemm_xw_mfma_k(const _Float16* __restrict__ A16,
                    const _Float16* __restrict__ W16T,
                    const float* __restrict__ bf, const float* __restrict__ bb,
                    _Float16* __restrict__ Gout)
{
    const int m0  = blockIdx.x * 128;
    const int n0  = blockIdx.y * 128;
    const int dir = blockIdx.z;
    const float* bias = dir ? bb : bf;
    const _Float16* Wd = W16T + (size_t)dir * 640 * 320;

    __shared__ _Float16 As[128][40];
    __shared__ _Float16 Bs[128][40];

    const int tid  = threadIdx.x;
    const int lane = tid & 63;
    const int w    = tid >> 6;
    const int wm   = w >> 1, wn = w & 1;
    const int r16  = lane & 15, q = lane >> 4;

    const int srow  = tid >> 1;
    const int sslot = (tid & 1) * 16;

    f4v acc[4][4];
    #pragma unroll
    for (int i = 0; i < 4; ++i)
        #pragma unroll
        for (int j = 0; j < 4; ++j) acc[i][j] = (f4v){0.f,0.f,0.f,0.f};

    for (int k0 = 0; k0 < 320; k0 += 32) {
        h8v av0 = *(const h8v*)&A16[(size_t)(m0 + srow) * 320 + k0 + sslot];
        h8v av1 = *(const h8v*)&A16[(size_t)(m0 + srow) * 320 + k0 + sslot + 8];
        h8v bv0 = *(const h8v*)&Wd [(size_t)(n0 + srow) * 320 + k0 + sslot];
        h8v bv1 = *(const h8v*)&Wd [(size_t)(n0 + srow) * 320 + k0 + sslot + 8];
        __syncthreads();
        *(h8v*)&As[srow][sslot]     = av0;
        *(h8v*)&As[srow][sslot + 8] = av1;
        *(h8v*)&Bs[srow][sslot]     = bv0;
        *(h8v*)&Bs[srow][sslot + 8] = bv1;
        __syncthreads();

        h8v af[4], bfr[4];
        #pragma unroll
        for (int mi = 0; mi < 4; ++mi)
            af[mi] = *(const h8v*)&As[wm*64 + mi*16 + r16][q*8];
        #pragma unroll
        for (int ni = 0; ni < 4; ++ni)
            bfr[ni] = *(const h8v*)&Bs[wn*64 + ni*16 + r16][q*8];
        #pragma unroll
        for (int mi = 0; mi < 4; ++mi)
            #pragma unroll
            for (int ni = 0; ni < 4; ++ni)
                acc[mi][ni] = __builtin_amdgcn_mfma_f32_16x16x32_f16(
                                  af[mi], bfr[ni], acc[mi][ni], 0, 0, 0);
    }

    #pragma unroll
    for (int ni = 0; ni < 4; ++ni) {
        int n = n0 + wn*64 + ni*16 + r16;
        if (n >= G4v) continue;
        float bn = bias[n];
        #pragma unroll
        for (int mi = 0; mi < 4; ++mi) {
            #pragma unroll
            for (int r = 0; r < 4; ++r) {
                int row = m0 + wm*64 + mi*16 + q*4 + r;
                int b   = row >> 7;
                int s   = row & 127;
                Gout[(((size_t)dir * Sv + s) * Bv + b) * G4v + n] =
                    (_Float16)(acc[mi][ni][r] + bn);
            }
        }
    }
}

// ------------------------------------------------------------------
// fast transcendentals (validated r8: absmax unchanged at 0.03125)
// ------------------------------------------------------------------
__device__ __forceinline__ float sigm_f(float x)
{
    return __builtin_amdgcn_rcpf(1.f + __expf(-x));
}
__device__ __forceinline__ float tanh_f(float x)
{
    float e = __expf(-2.f * __builtin_fabsf(x));
    float r = (1.f - e) * __builtin_amdgcn_rcpf(1.f + e);
    return __builtin_copysignf(r, x);
}

// ------------------------------------------------------------------
// MFMA LSTM recurrence v4 = round-6 structure (128 blocks, 4 batches,
// A=h / B=Wh-registers, g_sh transpose) + fp16 G + depth-2 prefetch +
// fast gate math. G stream is the measured bottleneck: fp16 halves
// lines/step and makes G L3-resident; two steps of prefetch cover.
// ------------------------------------------------------------------
__global__ __launch_bounds__(640, 1)
void lstm_mfma_k(const _Float16* __restrict__ G16,  // [2][S][B][600] fp16
                 const float* __restrict__ Wh_f, const float* __restrict__ Wh_b,
                 float* __restrict__ out_src,       // [B][S][300]
                 float* __restrict__ out_cell)      // [B][300]
{
    const int blk = blockIdx.x;          // 0..127
    const int dir = blk & 1;
    const int b0  = (blk >> 1) * 4;
    const float* Wh = dir ? Wh_b : Wh_f;
    const _Float16* Gd = G16 + (size_t)dir * Sv * Bv * G4v;

    const int tid  = threadIdx.x;
    const int w    = tid >> 6;           // wave 0..9
    const int lane = tid & 63;
    const int q    = lane >> 4;          // 0..3
    const int cp   = lane & 15;          // 0..15
    const int hcol = w * 16 + cp;        // 0..159
    const bool colok = (hcol < Hv);
    const int hc   = colok ? hcol : 0;   // clamped: dead lanes read real
                                         // (finite) G, never OOB/garbage
    const int rp   = q;                  // batch row this lane owns

    __shared__ _Float16 h_sh[2][16][168];
    __shared__ float    g_sh[10][4][16][4];   // [wave][gate][col][row]

    // ---- one-time: Wh B-fragments in registers ----
    h8v Bf[4][5];
    #pragma unroll
    for (int g = 0; g < 4; ++g) {
        #pragma unroll
        for (int ks = 0; ks < 5; ++ks) {
            h8v v;
            #pragma unroll
            for (int j = 0; j < 8; ++j) {
                int k = 32*ks + 8*q + j;
                float x = (k < Hv && colok) ? Wh[(size_t)k * G4v + g*Hv + hcol] : 0.f;
                v[j] = (_Float16)x;
            }
            Bf[g][ks] = v;
        }
    }

    for (int i = tid; i < 2*16*168; i += 640)
        ((_Float16*)h_sh)[i] = (_Float16)0.f;

    float c = 0.f;

    // ---- prologue: prefetch G for steps 0 and 1 (depth 2) ----
    _Float16 gA[4], gB[4];
    {
        int ss0 = dir ? (Sv - 1) : 0;
        int ss1 = dir ? (Sv - 2) : 1;
        const _Float16* p0 = Gd + ((size_t)ss0 * Bv + b0 + rp) * G4v;
        const _Float16* p1 = Gd + ((size_t)ss1 * Bv + b0 + rp) * G4v;
        #pragma unroll
        for (int g = 0; g < 4; ++g) {
            gA[g] = p0[g*Hv + hc];
            gB[g] = p1[g*Hv + hc];
        }
    }
    __syncthreads();

    int cur = 0;
    for (int s = 0; s < Sv; ++s) {
        const int ss = dir ? (Sv - 1 - s) : s;

        // ---- prefetch G for step s+2 (2 steps of latency cover) ----
        _Float16 gC[4];
        #pragma unroll
        for (int g = 0; g < 4; ++g) gC[g] = (_Float16)0.f;
        if (s + 2 < Sv) {
            int ss2 = dir ? (ss - 2) : (ss + 2);
            const _Float16* p = Gd + ((size_t)ss2 * Bv + b0 + rp) * G4v;
            #pragma unroll
            for (int g = 0; g < 4; ++g) gC[g] = p[g*Hv + hc];
        }

        // ---- MFMA: h @ Wh (A = h from LDS, B = Wh registers) ----
        f4v a0 = {0.f,0.f,0.f,0.f}, a1 = a0, a2 = a0, a3 = a0;
        #pragma unroll
        for (int ks = 0; ks < 5; ++ks) {
            h8v af = *(const h8v*)&h_sh[cur][cp][32*ks + 8*q];
            a0 = __builtin_amdgcn_mfma_f32_16x16x32_f16(af, Bf[0][ks], a0, 0, 0, 0);
            a1 = __builtin_amdgcn_mfma_f32_16x16x32_f16(af, Bf[1][ks], a1, 0, 0, 0);
            a2 = __builtin_amdgcn_mfma_f32_16x16x32_f16(af, Bf[2][ks], a2, 0, 0, 0);
            a3 = __builtin_amdgcn_mfma_f32_16x16x32_f16(af, Bf[3][ks], a3, 0, 0, 0);
        }

        // ---- wave-private transpose (q==0 lanes hold all rows) ----
        if (q == 0) {
            *(f4v*)&g_sh[w][0][cp][0] = a0;
            *(f4v*)&g_sh[w][1][cp][0] = a1;
            *(f4v*)&g_sh[w][2][cp][0] = a2;
            *(f4v*)&g_sh[w][3][cp][0] = a3;
        }
        float gi = g_sh[w][0][cp][rp] + (float)gA[0];
        float gf = g_sh[w][1][cp][rp] + (float)gA[1];
        float gg = g_sh[w][2][cp][rp] + (float)gA[2];
        float go = g_sh[w][3][cp][rp] + (float)gA[3];

        float I  = sigm_f(gi);
        float F  = sigm_f(gf);
        float Gt = tanh_f(gg);
        float O  = sigm_f(go);
        c = F * c + I * Gt;
        float h = O * tanh_f(c);

        h_sh[cur ^ 1][rp][hcol] = (_Float16)h;
        if (colok)
            out_src[(((size_t)(b0 + rp)) * Sv + ss) * (2*Hv) + dir*Hv + hcol] = h;

        #pragma unroll
        for (int g = 0; g < 4; ++g) { gA[g] = gB[g]; gB[g] = gC[g]; }
        cur ^= 1;

        // lgkmcnt-only barrier (LDS visibility; VMEM prefetch stays in flight)
        asm volatile("s_waitcnt lgkmcnt(0)" ::: "memory");
        __builtin_amdgcn_s_barrier();
        __builtin_amdgcn_sched_barrier(0);
    }

    if (colok)
        out_cell[(size_t)(b0 + rp) * (2*Hv) + dir*Hv + hcol] = c;
}

// ------------------------------------------------------------------
// transpose src_encoding: out_src fp32 [B][S][300] -> hi/lo fp16 [B][320][128]
// ------------------------------------------------------------------
__global__ __launch_bounds__(256)
void trans_enc_k(const float* __restrict__ enc,
                 _Float16* __restrict__ hi, _Float16* __restrict__ lo)
{
    const int b  = blockIdx.z;
    const int s0 = blockIdx.x * 64;
    const int n0 = blockIdx.y * 64;
    __shared__ float t[64][65];
    const int tid = threadIdx.x;
    const int j  = tid & 63;
    const int i0 = (tid >> 6) * 16;
    #pragma unroll
    for (int ii = 0; ii < 16; ++ii) {
        int i = i0 + ii;
        int n = n0 + j;
        t[i][j] = (n < Dv) ? enc[((size_t)b*Sv + s0 + i)*Dv + n] : 0.f;
    }
    __syncthreads();
    #pragma unroll
    for (int ii = 0; ii < 16; ++ii) {
        int nr = i0 + ii;
        float v = t[j][nr];
        _Float16 hh = (_Float16)v;
        float l = v - (float)hh;
        size_t o = ((size_t)b*320 + n0 + nr)*128 + s0 + j;
        hi[o] = hh;
        lo[o] = (_Float16)l;
    }
}

// ------------------------------------------------------------------
// MFMA cosine-sim: sim16[b][m][s] = (cmp16[b,m,:].src16[b,s,:])/(cn*sn)
// ------------------------------------------------------------------
__global__ __launch_bounds__(256)
void gemm_sim_mfma_k(const _Float16* __restrict__ cmp16,  // [Bz][M][320]
                     const _Float16* __restrict__ src16,  // [B*128][320]
                     const float* __restrict__ cn, const float* __restrict__ sn,
                     int M, _Float16* __restrict__ sim16) // [Bz][M][128]
{
    const int m0 = blockIdx.x * 128;
    const int b  = blockIdx.z;
    const _Float16* A  = cmp16 + (size_t)b * M * 320;
    const _Float16* Bm = src16 + (size_t)b * 128 * 320;

    __shared__ _Float16 As[128][40];
    __shared__ _Float16 Bs[128][40];

    const int tid  = threadIdx.x;
    const int lane = tid & 63;
    const int w    = tid >> 6;
    const int wm   = w >> 1, wn = w & 1;
    const int r16  = lane & 15, q = lane >> 4;

    const int srow  = tid >> 1;
    const int sslot = (tid & 1) * 16;
    const int arow  = (m0 + srow < M) ? (m0 + srow) : 0;

    f4v acc[4][4];
    #pragma unroll
    for (int i = 0; i < 4; ++i)
        #pragma unroll
        for (int j = 0; j < 4; ++j) acc[i][j] = (f4v){0.f,0.f,0.f,0.f};

    for (int k0 = 0; k0 < 320; k0 += 32) {
        h8v av0 = *(const h8v*)&A [(size_t)arow * 320 + k0 + sslot];
        h8v av1 = *(const h8v*)&A [(size_t)arow * 320 + k0 + sslot + 8];
        h8v bv0 = *(const h8v*)&Bm[(size_t)srow * 320 + k0 + sslot];
        h8v bv1 = *(const h8v*)&Bm[(size_t)srow * 320 + k0 + sslot + 8];
        __syncthreads();
        *(h8v*)&As[srow][sslot]     = av0;
        *(h8v*)&As[srow][sslot + 8] = av1;
        *(h8v*)&Bs[srow][sslot]     = bv0;
        *(h8v*)&Bs[srow][sslot + 8] = bv1;
        __syncthreads();

        h8v af[4], bfr[4];
        #pragma unroll
        for (int mi = 0; mi < 4; ++mi)
            af[mi] = *(const h8v*)&As[wm*64 + mi*16 + r16][q*8];
        #pragma unroll
        for (int ni = 0; ni < 4; ++ni)
            bfr[ni] = *(const h8v*)&Bs[wn*64 + ni*16 + r16][q*8];
        #pragma unroll
        for (int mi = 0; mi < 4; ++mi)
            #pragma unroll
            for (int ni = 0; ni < 4; ++ni)
                acc[mi][ni] = __builtin_amdgcn_mfma_f32_16x16x32_f16(
                                  af[mi], bfr[ni], acc[mi][ni], 0, 0, 0);
    }

    #pragma unroll
    for (int ni = 0; ni < 4; ++ni) {
        int s = wn*64 + ni*16 + r16;
        float snv = sn[(size_t)b * 128 + s];
        #pragma unroll
        for (int mi = 0; mi < 4; ++mi) {
            #pragma unroll
            for (int r = 0; r < 4; ++r) {
                int m = m0 + wm*64 + mi*16 + q*4 + r;
                if (m < M) {
                    float v = acc[mi][ni][r] / (cn[(size_t)b * M + m] * snv);
                    sim16[((size_t)b * M + m) * 128 + s] = (_Float16)v;
                }
            }
        }
    }
}

// ------------------------------------------------------------------
// Fused context + type-encoder epilogue
// ------------------------------------------------------------------
__global__ __launch_bounds__(256, 2)
void gemm_ctx_fused_k(const _Float16* __restrict__ sim16,  // [Bz][M][128]
                      const _Float16* __restrict__ encHi,
                      const _Float16* __restrict__ encLo,  // [B][320][128]
                      const float* __restrict__ emb,       // [Bz][M][300]
                      const float* __restrict__ hot,       // [Bz][M][hd]
                      const float* __restrict__ W,         // [hd][300]
                      const float* __restrict__ bias,      // [300]
                      int M, int hd, float* __restrict__ outp)
{
    const int b  = blockIdx.z;
    const int m0 = blockIdx.x * 64;
    const int tid = threadIdx.x;
    const int lane = tid & 63;
    const int w = tid >> 6;
    const int q = lane >> 4, cp = lane & 15;

    __shared__ _Float16 As[64][136];
    __shared__ float Wsh[9*304];
    __shared__ float bsh[304];
    __shared__ float hotsh[64*9];

    {
        const int srow = tid >> 2;
        const int scol = (tid & 3) * 32;
        const _Float16* src = sim16 + ((size_t)b * M + m0 + srow) * 128 + scol;
        *(h8v*)&As[srow][scol]      = *(const h8v*)&src[0];
        *(h8v*)&As[srow][scol + 8]  = *(const h8v*)&src[8];
        *(h8v*)&As[srow][scol + 16] = *(const h8v*)&src[16];
        *(h8v*)&As[srow][scol + 24] = *(const h8v*)&src[24];
    }
    for (int i = tid; i < hd*304; i += 256) {
        int jj = i / 304, nn = i - jj*304;
        Wsh[i] = (nn < Dv) ? W[(size_t)jj * Dv + nn] : 0.f;
    }
    for (int i = tid; i < 304; i += 256) bsh[i] = (i < Dv) ? bias[i] : 0.f;
    for (int i = tid; i < 64*hd; i += 256) hotsh[i] = hot[((size_t)b * M + m0) * hd + i];
    __syncthreads();

    h8v af[4][4];
    #pragma unroll
    for (int mi = 0; mi < 4; ++mi)
        #pragma unroll
        for (int ks = 0; ks < 4; ++ks)
            af[mi][ks] = *(const h8v*)&As[mi*16 + cp][32*ks + 8*q];

    f4v acc[4][5];
    #pragma unroll
    for (int mi = 0; mi < 4; ++mi)
        #pragma unroll
        for (int nt = 0; nt < 5; ++nt) acc[mi][nt] = (f4v){0.f,0.f,0.f,0.f};

    const int nbase = w * 80;
    #pragma unroll
    for (int pass = 0; pass < 2; ++pass) {
        const _Float16* encp = pass ? encLo : encHi;
        #pragma unroll
        for (int nt = 0; nt < 5; ++nt) {
            int n = nbase + nt*16 + cp;
            const _Float16* bp = encp + ((size_t)b * 320 + n) * 128 + 8*q;
            h8v b0 = *(const h8v*)&bp[0];
            h8v b1 = *(const h8v*)&bp[32];
            h8v b2 = *(const h8v*)&bp[64];
            h8v b3 = *(const h8v*)&bp[96];
            #pragma unroll
            for (int mi = 0; mi < 4; ++mi) {
                acc[mi][nt] = __builtin_amdgcn_mfma_f32_16x16x32_f16(af[mi][0], b0, acc[mi][nt], 0, 0, 0);
                acc[mi][nt] = __builtin_amdgcn_mfma_f32_16x16x32_f16(af[mi][1], b1, acc[mi][nt], 0, 0, 0);
                acc[mi][nt] = __builtin_amdgcn_mfma_f32_16x16x32_f16(af[mi][2], b2, acc[mi][nt], 0, 0, 0);
                acc[mi][nt] = __builtin_amdgcn_mfma_f32_16x16x32_f16(af[mi][3], b3, acc[mi][nt], 0, 0, 0);
            }
        }
    }

    #pragma unroll
    for (int nt = 0; nt < 5; ++nt) {
        int n = nbase + nt*16 + cp;
        if (n >= Dv) continue;
        float bn = bsh[n];
        #pragma unroll
        for (int mi = 0; mi < 4; ++mi) {
            #pragma unroll
            for (int r = 0; r < 4; ++r) {
                int ml = mi*16 + 4*q + r;
                int m  = m0 + ml;
                float v = acc[mi][nt][r] + bn + emb[((size_t)b * M + m) * Dv + n];
                for (int jj = 0; jj < hd; ++jj)
                    v = fmaf(hotsh[ml*hd + jj], Wsh[jj*304 + n], v);
                outp[((size_t)b * M + m) * Dv + n] = v;
            }
        }
    }
}

// ------------------------------------------------------------------
extern "C" void kernel_launch(void* const* d_in, const int* in_sizes, int n_in,
                              void* d_out, int out_size, void* d_ws, size_t ws_size,
                              hipStream_t stream)
{
    (void)in_sizes; (void)n_in; (void)out_size; (void)ws_size;
    const float* src_emb = (const float*)d_in[0];
    const float* col_emb = (const float*)d_in[1];
    const float* tab_emb = (const float*)d_in[2];
    const float* col_hot = (const float*)d_in[3];
    const float* tab_hot = (const float*)d_in[4];
    const float* Wx_f = (const float*)d_in[5];
    const float* Wh_f = (const float*)d_in[6];
    const float* b_f  = (const float*)d_in[7];
    const float* Wx_b = (const float*)d_in[8];
    const float* Wh_b = (const float*)d_in[9];
    const float* b_b  = (const float*)d_in[10];
    const float* W_col = (const float*)d_in[11];
    const float* b_col = (const float*)d_in[12];
    const float* W_tab = (const float*)d_in[13];
    const float* b_tab = (const float*)d_in[14];

    float* out      = (float*)d_out;
    float* out_src  = out;                       // [256][128][300]
    float* out_col  = out + 9830400;             // [256][256][300]
    float* out_tab  = out + 29491200;            // [256][64][300]
    float* out_cell = out + 34406400;            // [256][300]

    float* ws = (float*)d_ws;
    _Float16* Gbuf16 = (_Float16*)ws;            // [2][128][256][600] fp16 = 78.6MB
    _Float16* encHi    = (_Float16*)(ws);             // reused AFTER lstm
    _Float16* encLo    = (_Float16*)(ws + 5242880);
    _Float16* sim16_col= (_Float16*)(ws + 11000000);
    _Float16* sim16_tab= (_Float16*)(ws + 16000000);
    float* sn = ws + 39321600;
    float* cn = sn + 32768;
    float* tn = cn + 65536;

    _Float16* A16   = (_Float16*)(out + 9830400);          // [32768][320]
    _Float16* W16T  = A16 + (size_t)32768 * 320;           // [2][640][320]
    _Float16* col16 = (_Float16*)(out + 15278080);         // [65536][320]
    _Float16* tab16 = (_Float16*)(out + 29491200);         // [16384][320]

    // 0. fp16 conversions
    conv_a16_k<<<32768*80/256, 256, 0, stream>>>(src_emb, A16);
    conv_a16_k<<<65536*80/256, 256, 0, stream>>>(col_emb, col16);
    conv_a16_k<<<16384*80/256, 256, 0, stream>>>(tab_emb, tab16);
    conv_w16_k<<<dim3(640, 2), 320, 0, stream>>>(Wx_f, Wx_b, W16T);

    // 1. norms
    row_norm_k<<<32768/4, 256, 0, stream>>>(src_emb, 32768, sn);
    row_norm_k<<<65536/4, 256, 0, stream>>>(col_emb, 65536, cn);
    row_norm_k<<<16384/4, 256, 0, stream>>>(tab_emb, 16384, tn);

    // 2. input projection (MFMA, fp16 G output)
    gemm_xw_mfma_k<<<dim3(256, 5, 2), 256, 0, stream>>>(A16, W16T, b_f, b_b, Gbuf16);

    // 3. recurrence (v4: r6 structure + fp16 G + depth-2 prefetch)
    lstm_mfma_k<<<128, 640, 0, stream>>>(Gbuf16, Wh_f, Wh_b, out_src, out_cell);

    // 4. transpose + split src_encoding (G now dead)
    trans_enc_k<<<dim3(2, 5, 256), 256, 0, stream>>>(out_src, encHi, encLo);

    // 5. cosine similarity (MFMA)
    gemm_sim_mfma_k<<<dim3(2, 1, 256), 256, 0, stream>>>(col16, A16, cn, sn, 256, sim16_col);
    gemm_sim_mfma_k<<<dim3(1, 1, 256), 256, 0, stream>>>(tab16, A16, tn, sn, 64,  sim16_tab);

    // 6. fused context + type encoder
    gemm_ctx_fused_k<<<dim3(4, 1, 256), 256, 0, stream>>>(
        sim16_col, encHi, encLo, col_emb, col_hot, W_col, b_col, 256, 9, out_col);
    gemm_ctx_fused_k<<<dim3(1, 1, 256), 256, 0, stream>>>(
        sim16_tab, encHi, encLo, tab_emb, tab_hot, W_tab, b_tab, 64, 5, out_tab);
}